// Round 1
// baseline (241.554 us; speedup 1.0000x reference)
//
#include <hip/hip_runtime.h>

// Problem constants (from reference):
//   x:    (B=2, C=8, F=80, N=128, N=128) fp32
//   quad: (H=512, W=1024) int32 in [0, F)
//   uv:   (H, W, 2) fp32 in [0, N-1)
//   out:  (B, C, H, W) fp32
#define BC   16                 // B*C
#define FD   80
#define ND   128
#define NN   (ND * ND)          // 16384
#define HW   (512 * 1024)       // 524288 = 2^19
#define HW_SHIFT 19

__global__ __launch_bounds__(256)
void resample_uv_kernel(const float* __restrict__ x,
                        const int*   __restrict__ quad,
                        const float2* __restrict__ uv2,
                        float* __restrict__ out)
{
    const int gid = blockIdx.x * 256 + threadIdx.x;   // bc*HW + pix
    const int pix = gid & (HW - 1);
    const int bc  = gid >> HW_SHIFT;

    // Coalesced per-pixel metadata loads (L2-hit for bc > 0).
    const float2 t = uv2[pix];
    const int    f = quad[pix];

    const float u = t.x;
    const float v = t.y;

    int u0 = (int)floorf(u);
    int v0 = (int)floorf(v);
    u0 = min(max(u0, 0), ND - 2);
    v0 = min(max(v0, 0), ND - 2);

    const float du = u - (float)u0;
    const float dv = v - (float)v0;

    const float w00 = (1.0f - du) * (1.0f - dv);
    const float w01 = du * (1.0f - dv);
    const float w10 = (1.0f - du) * dv;
    const float w11 = du * dv;

    // Gather 4 texels from this channel's patch f.
    const float* p = x + ((size_t)bc * FD + (size_t)f) * NN + v0 * ND + u0;
    const float g00 = p[0];
    const float g01 = p[1];
    const float g10 = p[ND];
    const float g11 = p[ND + 1];

    out[gid] = g00 * w00 + g01 * w01 + g10 * w10 + g11 * w11;
}

extern "C" void kernel_launch(void* const* d_in, const int* in_sizes, int n_in,
                              void* d_out, int out_size, void* d_ws, size_t ws_size,
                              hipStream_t stream)
{
    const float*  x    = (const float*)d_in[0];
    const int*    quad = (const int*)d_in[1];
    const float2* uv2  = (const float2*)d_in[2];
    float*        out  = (float*)d_out;

    const int total  = BC * HW;                  // 8,388,608
    const int block  = 256;
    const int grid   = total / block;            // 32768

    resample_uv_kernel<<<grid, block, 0, stream>>>(x, quad, uv2, out);
}